// Round 1
// baseline (1291.918 us; speedup 1.0000x reference)
//
#include <hip/hip_runtime.h>
#include <cstdio>
#include <cstdint>

#define LRELU 0.2f
#define BN_EPS 1e-5f

__device__ inline unsigned short f2bf(float f) {
  unsigned int u = __float_as_uint(f);
  u += 0x7fffu + ((u >> 16) & 1u);   // RNE
  return (unsigned short)(u >> 16);
}
__device__ inline float bcastf(float v, int l) {
  return __uint_as_float(__builtin_amdgcn_readlane(__float_as_uint(v), l));
}

// ---------------- CSR build ----------------
__global__ void k_deg(const int* __restrict__ dst, int* __restrict__ deg, int E) {
  int i = blockIdx.x * blockDim.x + threadIdx.x;
  if (i < E) atomicAdd(&deg[dst[i]], 1);
}

__global__ void k_scan_tile(const int* __restrict__ deg, int* __restrict__ offs,
                            int* __restrict__ tilesum, int N) {
  __shared__ int sh[256];
  int i = blockIdx.x * 256 + threadIdx.x;
  int v = (i < N) ? deg[i] : 0;
  sh[threadIdx.x] = v;
  __syncthreads();
  for (int s = 1; s < 256; s <<= 1) {
    int t = (threadIdx.x >= s) ? sh[threadIdx.x - s] : 0;
    __syncthreads();
    sh[threadIdx.x] += t;
    __syncthreads();
  }
  if (i < N) offs[i] = sh[threadIdx.x] - v;   // tile-local exclusive
  if (threadIdx.x == 255) tilesum[blockIdx.x] = sh[255];
}

__global__ void k_scan_sums(const int* __restrict__ tilesum, int* __restrict__ tilepre,
                            int nb, int* __restrict__ offs, int N) {
  if (threadIdx.x == 0 && blockIdx.x == 0) {
    int run = 0;
    for (int b = 0; b < nb; b++) { tilepre[b] = run; run += tilesum[b]; }
    offs[N] = run;   // == E
  }
}

__global__ void k_addfix(int* __restrict__ offs, int* __restrict__ cursor,
                         const int* __restrict__ tilepre, int N) {
  int i = blockIdx.x * blockDim.x + threadIdx.x;
  if (i < N) {
    int v = offs[i] + tilepre[i >> 8];
    offs[i] = v;
    cursor[i] = v;
  }
}

__global__ void k_scatter(const int* __restrict__ src, const int* __restrict__ dst,
                          int* __restrict__ cursor, int* __restrict__ srcs, int E) {
  int i = blockIdx.x * blockDim.x + threadIdx.x;
  if (i < E) {
    int pos = atomicAdd(&cursor[dst[i]], 1);
    srcs[pos] = src[i];
  }
}

// ---------------- GEMM + attention logits ----------------
// in: [N,F] fp32 (optionally BN+ReLU fused on load). W: [F,128] fp32.
// out: h [N,128] bf16, als/ald [N,4] fp32.
template <int F, bool BN>
__global__ __launch_bounds__(128) void k_gemm(
    const float* __restrict__ in, const float* __restrict__ W,
    const float* __restrict__ asrc, const float* __restrict__ adst,
    const float* __restrict__ bnsc, const float* __restrict__ bnsh,
    unsigned short* __restrict__ h, float* __restrict__ als,
    float* __restrict__ ald, int N) {
  constexpr int ROWS = 8;
  constexpr int CH = (F > 64) ? 64 : F;
  constexpr int XR = (F + 63) / 64;
  __shared__ float Wl[CH][128];
  const int tid = threadIdx.x;
  const int lane = tid & 63;
  const int row0 = blockIdx.x * ROWS;

  // X rows in registers (each wave holds its own copy; broadcast via readlane)
  float xr[ROWS][XR];
#pragma unroll
  for (int r = 0; r < ROWS; r++) {
    int row = row0 + r;
#pragma unroll
    for (int p = 0; p < XR; p++) {
      int f = p * 64 + lane;
      float v = 0.f;
      if (row < N && f < F) {
        v = in[(long)row * F + f];
        if (BN) v = fmaxf(0.f, v * bnsc[f] + bnsh[f]);
      }
      xr[r][p] = v;
    }
  }

  float acc[ROWS];
#pragma unroll
  for (int r = 0; r < ROWS; r++) acc[r] = 0.f;

#pragma unroll
  for (int f0 = 0; f0 < F; f0 += CH) {
    __syncthreads();
#pragma unroll
    for (int k = 0; k < CH; k++) Wl[k][tid] = W[(f0 + k) * 128 + tid];
    __syncthreads();
#pragma unroll
    for (int f = 0; f < CH; f++) {
      const int ff = f0 + f;
      float wv = Wl[f][tid];
#pragma unroll
      for (int r = 0; r < ROWS; r++)
        acc[r] += bcastf(xr[r][ff >> 6], ff & 63) * wv;
    }
  }

  const float av = asrc[tid], dv = adst[tid];
  const int head = tid >> 5;
#pragma unroll
  for (int r = 0; r < ROWS; r++) {
    int row = row0 + r;
    if (row < N) {
      float v = acc[r];
      h[(long)row * 128 + tid] = f2bf(v);
      float p = v * av, q = v * dv;
      p += __shfl_down(p, 16, 32); q += __shfl_down(q, 16, 32);
      p += __shfl_down(p, 8, 32);  q += __shfl_down(q, 8, 32);
      p += __shfl_down(p, 4, 32);  q += __shfl_down(q, 4, 32);
      p += __shfl_down(p, 2, 32);  q += __shfl_down(q, 2, 32);
      p += __shfl_down(p, 1, 32);  q += __shfl_down(q, 1, 32);
      if ((tid & 31) == 0) { als[row * 4 + head] = p; ald[row * 4 + head] = q; }
    }
  }
}

// ---------------- per-dst aggregation (softmax fused, one wave/node) ----------------
__global__ __launch_bounds__(256) void k_agg(
    const unsigned int* __restrict__ h2, const float* __restrict__ als,
    const float* __restrict__ ald, const int* __restrict__ offs,
    const int* __restrict__ srcs, const float* __restrict__ bias,
    float* __restrict__ y, int N) {
  int node = blockIdx.x * 4 + (threadIdx.x >> 6);
  if (node >= N) return;
  int lane = threadIdx.x & 63;   // lane owns j = 2*lane, 2*lane+1
  int head = lane >> 4;          // (2*lane)>>5
  float ad = ald[node * 4 + head];
  int beg = offs[node], end = offs[node + 1];
  float ax = 0.f, ay = 0.f, den = 0.f;
  for (int e = beg; e < end; e++) {
    int s = srcs[e];
    float as = als[s * 4 + head];
    float ev = as + ad;
    ev = (ev >= 0.f) ? ev : LRELU * ev;
    float w = __expf(ev);            // no segment_max needed: |e| small, fp32 exp safe
    unsigned int u = h2[s * 64 + lane];
    float hx = __uint_as_float(u << 16);
    float hy = __uint_as_float(u & 0xffff0000u);
    den += w;
    ax += w * hx; ay += w * hy;
  }
  float r = (den > 0.f) ? (1.f / den) : 0.f;   // empty segment -> 0 (matches ref)
  ax *= r; ay *= r;
  // sum over 4 heads: lanes {i, i^16, i^32, i^48}
  ax += __shfl_xor(ax, 16); ay += __shfl_xor(ay, 16);
  ax += __shfl_xor(ax, 32); ay += __shfl_xor(ay, 32);
  if (lane < 16) {
    float2 b2 = ((const float2*)bias)[lane];
    float2 o;
    o.x = 0.25f * ax + b2.x;
    o.y = 0.25f * ay + b2.y;
    ((float2*)(y + (long)node * 32))[lane] = o;
  }
}

// ---------------- batch norm ----------------
__global__ __launch_bounds__(256) void k_bnstats(const float* __restrict__ y,
                                                 float* __restrict__ stats, int N) {
  __shared__ float s1[32], s2[32];
  if (threadIdx.x < 32) { s1[threadIdx.x] = 0.f; s2[threadIdx.x] = 0.f; }
  __syncthreads();
  float a = 0.f, b = 0.f;
  int total = N * 32;
  for (int i = blockIdx.x * blockDim.x + threadIdx.x; i < total;
       i += gridDim.x * blockDim.x) {
    float v = y[i];
    a += v; b += v * v;
  }
  int c = threadIdx.x & 31;   // channel invariant: strides are multiples of 32
  atomicAdd(&s1[c], a); atomicAdd(&s2[c], b);
  __syncthreads();
  if (threadIdx.x < 32) {
    atomicAdd(&stats[threadIdx.x], s1[threadIdx.x]);
    atomicAdd(&stats[32 + threadIdx.x], s2[threadIdx.x]);
  }
}

__global__ void k_bnfinal(const float* __restrict__ stats, const float* __restrict__ g,
                          const float* __restrict__ be, float* __restrict__ sc,
                          float* __restrict__ sh, int N) {
  int c = threadIdx.x;
  if (c < 32) {
    float inv = 1.f / (float)N;
    float mu = stats[c] * inv;
    float var = stats[32 + c] * inv - mu * mu;   // biased, as in ref
    float s = g[c] * rsqrtf(var + BN_EPS);
    sc[c] = s;
    sh[c] = be[c] - mu * s;
  }
}

__global__ void k_copy4(const float4* __restrict__ s, float4* __restrict__ d, int n) {
  int i = blockIdx.x * blockDim.x + threadIdx.x;
  if (i < n) d[i] = s[i];
}

// ---------------- launch ----------------
extern "C" void kernel_launch(void* const* d_in, const int* in_sizes, int n_in,
                              void* d_out, int out_size, void* d_ws, size_t ws_size,
                              hipStream_t stream) {
  const float* x   = (const float*)d_in[0];
  const int*   ei  = (const int*)d_in[1];
  const float* ea  = (const float*)d_in[2];
  const float* W0  = (const float*)d_in[3];
  const float* as0 = (const float*)d_in[4];
  const float* ad0 = (const float*)d_in[5];
  const float* b0  = (const float*)d_in[6];
  const float* g0  = (const float*)d_in[7];
  const float* be0 = (const float*)d_in[8];
  const float* W1  = (const float*)d_in[9];
  const float* as1 = (const float*)d_in[10];
  const float* ad1 = (const float*)d_in[11];
  const float* b1  = (const float*)d_in[12];
  const float* g1  = (const float*)d_in[13];
  const float* be1 = (const float*)d_in[14];
  const float* W2  = (const float*)d_in[15];
  const float* as2 = (const float*)d_in[16];
  const float* ad2 = (const float*)d_in[17];
  const float* b2  = (const float*)d_in[18];

  const int N = in_sizes[0] / 128;
  const int E = in_sizes[1] / 2;
  const int* srcI = ei;
  const int* dstI = ei + E;

  char* w = (char*)d_ws;
  auto carve = [&](size_t bytes) -> void* {
    void* p = (void*)w;
    w += (bytes + 255) & ~(size_t)255;
    return p;
  };
  unsigned short* h = (unsigned short*)carve((size_t)N * 128 * 2);
  float* als        = (float*)carve((size_t)N * 4 * 4);
  float* ald        = (float*)carve((size_t)N * 4 * 4);
  float* y          = (float*)carve((size_t)N * 32 * 4);
  int* offs         = (int*)carve((size_t)(N + 1) * 4);
  int* cursor       = (int*)carve((size_t)N * 4);
  int* srcs         = (int*)carve((size_t)E * 4);
  int* deg          = (int*)carve((size_t)N * 4);
  const int nb = (N + 255) / 256;
  int* tilesum      = (int*)carve((size_t)nb * 4);
  int* tilepre      = (int*)carve((size_t)nb * 4);
  float* stats      = (float*)carve(128 * 4);
  float* bnsc       = (float*)carve(32 * 4);
  float* bnsh       = (float*)carve(32 * 4);
  if ((size_t)(w - (char*)d_ws) > ws_size) {
    fprintf(stderr, "GAT kernel: ws too small (%zu needed, %zu given)\n",
            (size_t)(w - (char*)d_ws), ws_size);
    return;
  }

  hipMemsetAsync(deg, 0, (size_t)N * 4, stream);
  hipMemsetAsync(stats, 0, 128 * 4, stream);

  k_deg<<<(E + 255) / 256, 256, 0, stream>>>(dstI, deg, E);
  k_scan_tile<<<nb, 256, 0, stream>>>(deg, offs, tilesum, N);
  k_scan_sums<<<1, 1, 0, stream>>>(tilesum, tilepre, nb, offs, N);
  k_addfix<<<nb, 256, 0, stream>>>(offs, cursor, tilepre, N);
  k_scatter<<<(E + 255) / 256, 256, 0, stream>>>(srcI, dstI, cursor, srcs, E);

  const int gGemm = (N + 7) / 8;
  const int gAgg  = (N + 3) / 4;
  float* out_nodes = (float*)d_out;
  float* out_ea    = out_nodes + (size_t)N * 32;

  // layer 0
  k_gemm<128, false><<<gGemm, 128, 0, stream>>>(x, W0, as0, ad0, nullptr, nullptr,
                                                h, als, ald, N);
  k_agg<<<gAgg, 256, 0, stream>>>((const unsigned int*)h, als, ald, offs, srcs, b0, y, N);
  k_bnstats<<<512, 256, 0, stream>>>(y, stats, N);
  k_bnfinal<<<1, 32, 0, stream>>>(stats, g0, be0, bnsc, bnsh, N);
  // layer 1 (BN+ReLU fused into GEMM input load)
  k_gemm<32, true><<<gGemm, 128, 0, stream>>>(y, W1, as1, ad1, bnsc, bnsh,
                                              h, als, ald, N);
  k_agg<<<gAgg, 256, 0, stream>>>((const unsigned int*)h, als, ald, offs, srcs, b1, y, N);
  k_bnstats<<<512, 256, 0, stream>>>(y, stats + 64, N);
  k_bnfinal<<<1, 32, 0, stream>>>(stats + 64, g1, be1, bnsc, bnsh, N);
  // layer 2 (writes node output directly to d_out)
  k_gemm<32, true><<<gGemm, 128, 0, stream>>>(y, W2, as2, ad2, bnsc, bnsh,
                                              h, als, ald, N);
  k_agg<<<gAgg, 256, 0, stream>>>((const unsigned int*)h, als, ald, offs, srcs, b2,
                                  out_nodes, N);
  // edge_attr passthrough
  const int n4 = E * 2;   // E*8 floats / 4
  k_copy4<<<(n4 + 255) / 256, 256, 0, stream>>>((const float4*)ea, (float4*)out_ea, n4);
}

// Round 2
// 752.061 us; speedup vs baseline: 1.7178x; 1.7178x over previous
//
#include <hip/hip_runtime.h>
#include <cstdio>
#include <cstdint>

#define LRELU 0.2f
#define BN_EPS 1e-5f

typedef short bf16x8 __attribute__((ext_vector_type(8)));
typedef float f32x4 __attribute__((ext_vector_type(4)));

__device__ inline unsigned short f2bf(float f) {
  unsigned int u = __float_as_uint(f);
  u += 0x7fffu + ((u >> 16) & 1u);   // RNE
  return (unsigned short)(u >> 16);
}
__device__ inline float bf2f(unsigned short v) {
  return __uint_as_float(((unsigned int)v) << 16);
}

// ---------------- CSR build ----------------
__global__ void k_deg(const int* __restrict__ dst, int* __restrict__ deg, int E) {
  int i = blockIdx.x * blockDim.x + threadIdx.x;
  if (i < E) atomicAdd(&deg[dst[i]], 1);
}

__global__ void k_scan_tile(const int* __restrict__ deg, int* __restrict__ offs,
                            int* __restrict__ tilesum, int N) {
  __shared__ int sh[256];
  int i = blockIdx.x * 256 + threadIdx.x;
  int v = (i < N) ? deg[i] : 0;
  sh[threadIdx.x] = v;
  __syncthreads();
  for (int s = 1; s < 256; s <<= 1) {
    int t = (threadIdx.x >= s) ? sh[threadIdx.x - s] : 0;
    __syncthreads();
    sh[threadIdx.x] += t;
    __syncthreads();
  }
  if (i < N) offs[i] = sh[threadIdx.x] - v;   // tile-local exclusive
  if (threadIdx.x == 255) tilesum[blockIdx.x] = sh[255];
}

__global__ void k_scan_sums(const int* __restrict__ tilesum, int* __restrict__ tilepre,
                            int nb, int* __restrict__ offs, int N) {
  if (threadIdx.x == 0 && blockIdx.x == 0) {
    int run = 0;
    for (int b = 0; b < nb; b++) { tilepre[b] = run; run += tilesum[b]; }
    offs[N] = run;   // == E
  }
}

__global__ void k_addfix(int* __restrict__ offs, int* __restrict__ cursor,
                         const int* __restrict__ tilepre, int N) {
  int i = blockIdx.x * blockDim.x + threadIdx.x;
  if (i < N) {
    int v = offs[i] + tilepre[i >> 8];
    offs[i] = v;
    cursor[i] = v;
  }
}

__global__ void k_scatter(const int* __restrict__ src, const int* __restrict__ dst,
                          int* __restrict__ cursor, int* __restrict__ srcs, int E) {
  int i = blockIdx.x * blockDim.x + threadIdx.x;
  if (i < E) {
    int pos = atomicAdd(&cursor[dst[i]], 1);
    srcs[pos] = src[i];
  }
}

// ---------------- weight cast+transpose: W[K][128] f32 -> Wt[128][K] bf16 ----
template <int K>
__global__ void k_castW(const float* __restrict__ W, unsigned short* __restrict__ Wt) {
  int o = blockIdx.x * blockDim.x + threadIdx.x;
  if (o < 128 * K) {
    int n = o / K, k = o - n * K;
    Wt[o] = f2bf(W[k * 128 + n]);
  }
}

// ---------------- MFMA GEMM + fused attention logits ----------------
// A: [N,K] (fp32 if AFP32, else bf16).  Wt: [128][K] bf16 (pre-transposed).
// out: h [N,128] bf16, als/ald [N,4] fp32.
// block = 256 (4 waves), wave computes 16 rows x 128 cols.
// A-frag layout (verified m118-m122): A[m=lane&15][k=(lane>>4)*8 + j]
// B-frag (dual):                      B[k=(lane>>4)*8 + j][n=lane&15]
// C/D layout (verified m89/m91):      col=lane&15, row=(lane>>4)*4 + reg
template <int K, bool AFP32>
__global__ __launch_bounds__(256) void k_mfma(
    const void* __restrict__ Ain, const unsigned short* __restrict__ Wt,
    const float* __restrict__ asrc, const float* __restrict__ adst,
    unsigned short* __restrict__ h, float* __restrict__ als,
    float* __restrict__ ald, int N) {
  __shared__ unsigned short lsh[4][16 * 132];   // stride 132: 2-way banks (free)
  const int wv   = threadIdx.x >> 6;
  const int lane = threadIdx.x & 63;
  const int quad = lane >> 4;
  const int col  = lane & 15;
  const int m0   = blockIdx.x * 64 + wv * 16;

  const int rowc = min(m0 + col, N - 1);   // clamp tail reads; stores guarded

  f32x4 acc[8];
#pragma unroll
  for (int t = 0; t < 8; t++) acc[t] = (f32x4){0.f, 0.f, 0.f, 0.f};

#pragma unroll
  for (int ks = 0; ks < K / 32; ks++) {
    const int k0 = ks * 32 + quad * 8;
    bf16x8 a;
    if constexpr (AFP32) {
      const float* ap = (const float*)Ain + (size_t)rowc * K + k0;
      float4 f0 = *(const float4*)ap;
      float4 f1 = *(const float4*)(ap + 4);
      a[0] = (short)f2bf(f0.x); a[1] = (short)f2bf(f0.y);
      a[2] = (short)f2bf(f0.z); a[3] = (short)f2bf(f0.w);
      a[4] = (short)f2bf(f1.x); a[5] = (short)f2bf(f1.y);
      a[6] = (short)f2bf(f1.z); a[7] = (short)f2bf(f1.w);
    } else {
      a = *(const bf16x8*)((const unsigned short*)Ain + (size_t)rowc * K + k0);
    }
#pragma unroll
    for (int t = 0; t < 8; t++) {
      bf16x8 b = *(const bf16x8*)(Wt + (size_t)(t * 16 + col) * K + k0);
      acc[t] = __builtin_amdgcn_mfma_f32_16x16x32_bf16(a, b, acc[t], 0, 0, 0);
    }
  }

  // stage C tile into LDS (bf16) for coalesced stores + fused logits
#pragma unroll
  for (int t = 0; t < 8; t++) {
#pragma unroll
    for (int j = 0; j < 4; j++) {
      lsh[wv][(quad * 4 + j) * 132 + col + 16 * t] = f2bf(acc[t][j]);
    }
  }
  __syncthreads();

  float as8[8], ad8[8];
#pragma unroll
  for (int j = 0; j < 8; j++) {
    as8[j] = asrc[col * 8 + j];
    ad8[j] = adst[col * 8 + j];
  }

#pragma unroll
  for (int i = 0; i < 4; i++) {
    const int row = i * 4 + quad;
    const int hrow = m0 + row;
    const unsigned short* rp = &lsh[wv][row * 132 + col * 8];
    ushort4 lo = *(const ushort4*)rp;
    ushort4 hi = *(const ushort4*)(rp + 4);
    float p = 0.f, q = 0.f, v;
    v = bf2f(lo.x); p += v * as8[0]; q += v * ad8[0];
    v = bf2f(lo.y); p += v * as8[1]; q += v * ad8[1];
    v = bf2f(lo.z); p += v * as8[2]; q += v * ad8[2];
    v = bf2f(lo.w); p += v * as8[3]; q += v * ad8[3];
    v = bf2f(hi.x); p += v * as8[4]; q += v * ad8[4];
    v = bf2f(hi.y); p += v * as8[5]; q += v * ad8[5];
    v = bf2f(hi.z); p += v * as8[6]; q += v * ad8[6];
    v = bf2f(hi.w); p += v * as8[7]; q += v * ad8[7];
    if (hrow < N) {
      ushort4* gp = (ushort4*)(h + (size_t)hrow * 128 + col * 8);
      gp[0] = lo; gp[1] = hi;
    }
    p += __shfl_xor(p, 1); p += __shfl_xor(p, 2);
    q += __shfl_xor(q, 1); q += __shfl_xor(q, 2);
    if ((lane & 3) == 0 && hrow < N) {
      const int head = col >> 2;
      als[hrow * 4 + head] = p;
      ald[hrow * 4 + head] = q;
    }
  }
}

// ---------------- per-dst aggregation (softmax fused, one wave/node) --------
__global__ __launch_bounds__(256) void k_agg(
    const unsigned int* __restrict__ h2, const float* __restrict__ als,
    const float* __restrict__ ald, const int* __restrict__ offs,
    const int* __restrict__ srcs, const float* __restrict__ bias,
    float* __restrict__ y, int N) {
  int node = blockIdx.x * 4 + (threadIdx.x >> 6);
  if (node >= N) return;
  int lane = threadIdx.x & 63;   // lane owns channels 2*lane, 2*lane+1
  int head = lane >> 4;
  float ad = ald[node * 4 + head];
  int beg = offs[node], end = offs[node + 1];
  float ax0 = 0.f, ay0 = 0.f, dn0 = 0.f;
  float ax1 = 0.f, ay1 = 0.f, dn1 = 0.f;
  int e = beg;
  // 4x unroll: 4 independent gathers in flight (hide L2/L3 latency)
  for (; e + 4 <= end; e += 4) {
    int s0 = srcs[e + 0], s1 = srcs[e + 1], s2 = srcs[e + 2], s3 = srcs[e + 3];
    float a0 = als[s0 * 4 + head], a1 = als[s1 * 4 + head];
    float a2 = als[s2 * 4 + head], a3 = als[s3 * 4 + head];
    unsigned int u0 = h2[(size_t)s0 * 64 + lane];
    unsigned int u1 = h2[(size_t)s1 * 64 + lane];
    unsigned int u2 = h2[(size_t)s2 * 64 + lane];
    unsigned int u3 = h2[(size_t)s3 * 64 + lane];
    float e0 = a0 + ad; e0 = (e0 >= 0.f) ? e0 : LRELU * e0;
    float e1 = a1 + ad; e1 = (e1 >= 0.f) ? e1 : LRELU * e1;
    float e2 = a2 + ad; e2 = (e2 >= 0.f) ? e2 : LRELU * e2;
    float e3 = a3 + ad; e3 = (e3 >= 0.f) ? e3 : LRELU * e3;
    float w0 = __expf(e0), w1 = __expf(e1), w2 = __expf(e2), w3 = __expf(e3);
    dn0 += w0; dn1 += w1; dn0 += w2; dn1 += w3;
    ax0 = fmaf(w0, __uint_as_float(u0 << 16), ax0);
    ay0 = fmaf(w0, __uint_as_float(u0 & 0xffff0000u), ay0);
    ax1 = fmaf(w1, __uint_as_float(u1 << 16), ax1);
    ay1 = fmaf(w1, __uint_as_float(u1 & 0xffff0000u), ay1);
    ax0 = fmaf(w2, __uint_as_float(u2 << 16), ax0);
    ay0 = fmaf(w2, __uint_as_float(u2 & 0xffff0000u), ay0);
    ax1 = fmaf(w3, __uint_as_float(u3 << 16), ax1);
    ay1 = fmaf(w3, __uint_as_float(u3 & 0xffff0000u), ay1);
  }
  for (; e < end; e++) {
    int s = srcs[e];
    float as = als[s * 4 + head];
    float ev = as + ad;
    ev = (ev >= 0.f) ? ev : LRELU * ev;
    float w = __expf(ev);
    unsigned int u = h2[(size_t)s * 64 + lane];
    dn0 += w;
    ax0 = fmaf(w, __uint_as_float(u << 16), ax0);
    ay0 = fmaf(w, __uint_as_float(u & 0xffff0000u), ay0);
  }
  float den = dn0 + dn1;
  float ax = ax0 + ax1, ay = ay0 + ay1;
  float r = (den > 0.f) ? (1.f / den) : 0.f;   // empty segment -> bias only
  ax *= r; ay *= r;
  // sum over 4 heads: lanes {i, i^16, i^32, i^48}
  ax += __shfl_xor(ax, 16); ay += __shfl_xor(ay, 16);
  ax += __shfl_xor(ax, 32); ay += __shfl_xor(ay, 32);
  if (lane < 16) {
    float2 b2 = ((const float2*)bias)[lane];
    float2 o;
    o.x = 0.25f * ax + b2.x;
    o.y = 0.25f * ay + b2.y;
    ((float2*)(y + (size_t)node * 32))[lane] = o;
  }
}

// ---------------- batch norm ----------------
__global__ __launch_bounds__(256) void k_bnstats(const float* __restrict__ y,
                                                 float* __restrict__ stats, int N) {
  __shared__ float s1[32], s2[32];
  if (threadIdx.x < 32) { s1[threadIdx.x] = 0.f; s2[threadIdx.x] = 0.f; }
  __syncthreads();
  float a = 0.f, b = 0.f;
  int total = N * 32;
  for (int i = blockIdx.x * blockDim.x + threadIdx.x; i < total;
       i += gridDim.x * blockDim.x) {
    float v = y[i];
    a += v; b += v * v;
  }
  int c = threadIdx.x & 31;   // channel invariant: strides multiple of 32
  atomicAdd(&s1[c], a); atomicAdd(&s2[c], b);
  __syncthreads();
  if (threadIdx.x < 32) {
    atomicAdd(&stats[threadIdx.x], s1[threadIdx.x]);
    atomicAdd(&stats[32 + threadIdx.x], s2[threadIdx.x]);
  }
}

__global__ void k_bnfinal(const float* __restrict__ stats, const float* __restrict__ g,
                          const float* __restrict__ be, float* __restrict__ sc,
                          float* __restrict__ sh, int N) {
  int c = threadIdx.x;
  if (c < 32) {
    float inv = 1.f / (float)N;
    float mu = stats[c] * inv;
    float var = stats[32 + c] * inv - mu * mu;   // biased, as in ref
    float s = g[c] * rsqrtf(var + BN_EPS);
    sc[c] = s;
    sh[c] = be[c] - mu * s;
  }
}

// BN + ReLU + cast to bf16: y [N,32] f32 -> yb [N,32] bf16
__global__ __launch_bounds__(256) void k_bncast(const float* __restrict__ y,
                                                const float* __restrict__ sc,
                                                const float* __restrict__ sh,
                                                unsigned short* __restrict__ yb,
                                                int N) {
  int i = blockIdx.x * blockDim.x + threadIdx.x;
  if (i >= N * 4) return;
  int base = i * 8;
  int c0 = base & 31;
  float4 f0 = *(const float4*)(y + base);
  float4 f1 = *(const float4*)(y + base + 4);
  bf16x8 o;
  o[0] = (short)f2bf(fmaxf(0.f, f0.x * sc[c0 + 0] + sh[c0 + 0]));
  o[1] = (short)f2bf(fmaxf(0.f, f0.y * sc[c0 + 1] + sh[c0 + 1]));
  o[2] = (short)f2bf(fmaxf(0.f, f0.z * sc[c0 + 2] + sh[c0 + 2]));
  o[3] = (short)f2bf(fmaxf(0.f, f0.w * sc[c0 + 3] + sh[c0 + 3]));
  o[4] = (short)f2bf(fmaxf(0.f, f1.x * sc[c0 + 4] + sh[c0 + 4]));
  o[5] = (short)f2bf(fmaxf(0.f, f1.y * sc[c0 + 5] + sh[c0 + 5]));
  o[6] = (short)f2bf(fmaxf(0.f, f1.z * sc[c0 + 6] + sh[c0 + 6]));
  o[7] = (short)f2bf(fmaxf(0.f, f1.w * sc[c0 + 7] + sh[c0 + 7]));
  *(bf16x8*)(yb + base) = o;
}

__global__ void k_copy4(const float4* __restrict__ s, float4* __restrict__ d, int n) {
  int i = blockIdx.x * blockDim.x + threadIdx.x;
  if (i < n) d[i] = s[i];
}

// ---------------- launch ----------------
extern "C" void kernel_launch(void* const* d_in, const int* in_sizes, int n_in,
                              void* d_out, int out_size, void* d_ws, size_t ws_size,
                              hipStream_t stream) {
  const float* x   = (const float*)d_in[0];
  const int*   ei  = (const int*)d_in[1];
  const float* ea  = (const float*)d_in[2];
  const float* W0  = (const float*)d_in[3];
  const float* as0 = (const float*)d_in[4];
  const float* ad0 = (const float*)d_in[5];
  const float* b0  = (const float*)d_in[6];
  const float* g0  = (const float*)d_in[7];
  const float* be0 = (const float*)d_in[8];
  const float* W1  = (const float*)d_in[9];
  const float* as1 = (const float*)d_in[10];
  const float* ad1 = (const float*)d_in[11];
  const float* b1  = (const float*)d_in[12];
  const float* g1  = (const float*)d_in[13];
  const float* be1 = (const float*)d_in[14];
  const float* W2  = (const float*)d_in[15];
  const float* as2 = (const float*)d_in[16];
  const float* ad2 = (const float*)d_in[17];
  const float* b2  = (const float*)d_in[18];

  const int N = in_sizes[0] / 128;
  const int E = in_sizes[1] / 2;
  const int* srcI = ei;
  const int* dstI = ei + E;

  char* w = (char*)d_ws;
  auto carve = [&](size_t bytes) -> void* {
    void* p = (void*)w;
    w += (bytes + 255) & ~(size_t)255;
    return p;
  };
  unsigned short* h  = (unsigned short*)carve((size_t)N * 128 * 2);
  unsigned short* yb = (unsigned short*)carve((size_t)N * 32 * 2);
  float* als        = (float*)carve((size_t)N * 4 * 4);
  float* ald        = (float*)carve((size_t)N * 4 * 4);
  float* y          = (float*)carve((size_t)N * 32 * 4);
  int* offs         = (int*)carve((size_t)(N + 1) * 4);
  int* cursor       = (int*)carve((size_t)N * 4);
  int* srcs         = (int*)carve((size_t)E * 4);
  int* deg          = (int*)carve((size_t)N * 4);
  const int nb = (N + 255) / 256;
  int* tilesum      = (int*)carve((size_t)nb * 4);
  int* tilepre      = (int*)carve((size_t)nb * 4);
  float* stats      = (float*)carve(128 * 4);
  float* bnsc       = (float*)carve(32 * 4);
  float* bnsh       = (float*)carve(32 * 4);
  unsigned short* Wt0 = (unsigned short*)carve(128 * 128 * 2);
  unsigned short* Wt1 = (unsigned short*)carve(128 * 32 * 2);
  unsigned short* Wt2 = (unsigned short*)carve(128 * 32 * 2);
  if ((size_t)(w - (char*)d_ws) > ws_size) {
    fprintf(stderr, "GAT kernel: ws too small (%zu needed, %zu given)\n",
            (size_t)(w - (char*)d_ws), ws_size);
    return;
  }

  hipMemsetAsync(deg, 0, (size_t)N * 4, stream);
  hipMemsetAsync(stats, 0, 128 * 4, stream);

  k_deg<<<(E + 255) / 256, 256, 0, stream>>>(dstI, deg, E);
  k_scan_tile<<<nb, 256, 0, stream>>>(deg, offs, tilesum, N);
  k_scan_sums<<<1, 1, 0, stream>>>(tilesum, tilepre, nb, offs, N);
  k_addfix<<<nb, 256, 0, stream>>>(offs, cursor, tilepre, N);
  k_scatter<<<(E + 255) / 256, 256, 0, stream>>>(srcI, dstI, cursor, srcs, E);

  k_castW<128><<<64, 256, 0, stream>>>(W0, Wt0);
  k_castW<32><<<16, 256, 0, stream>>>(W1, Wt1);
  k_castW<32><<<16, 256, 0, stream>>>(W2, Wt2);

  const int gGemm = (N + 63) / 64;
  const int gAgg  = (N + 3) / 4;
  const int gCast = (N * 4 + 255) / 256;
  float* out_nodes = (float*)d_out;
  float* out_ea    = out_nodes + (size_t)N * 32;

  // layer 0
  k_mfma<128, true><<<gGemm, 256, 0, stream>>>(x, Wt0, as0, ad0, h, als, ald, N);
  k_agg<<<gAgg, 256, 0, stream>>>((const unsigned int*)h, als, ald, offs, srcs, b0, y, N);
  k_bnstats<<<512, 256, 0, stream>>>(y, stats, N);
  k_bnfinal<<<1, 32, 0, stream>>>(stats, g0, be0, bnsc, bnsh, N);
  k_bncast<<<gCast, 256, 0, stream>>>(y, bnsc, bnsh, yb, N);
  // layer 1
  k_mfma<32, false><<<gGemm, 256, 0, stream>>>(yb, Wt1, as1, ad1, h, als, ald, N);
  k_agg<<<gAgg, 256, 0, stream>>>((const unsigned int*)h, als, ald, offs, srcs, b1, y, N);
  k_bnstats<<<512, 256, 0, stream>>>(y, stats + 64, N);
  k_bnfinal<<<1, 32, 0, stream>>>(stats + 64, g1, be1, bnsc, bnsh, N);
  k_bncast<<<gCast, 256, 0, stream>>>(y, bnsc, bnsh, yb, N);
  // layer 2 (writes node output directly to d_out)
  k_mfma<32, false><<<gGemm, 256, 0, stream>>>(yb, Wt2, as2, ad2, h, als, ald, N);
  k_agg<<<gAgg, 256, 0, stream>>>((const unsigned int*)h, als, ald, offs, srcs, b2,
                                  out_nodes, N);
  // edge_attr passthrough
  const int n4 = E * 2;   // E*8 floats / 4
  k_copy4<<<(n4 + 255) / 256, 256, 0, stream>>>((const float4*)ea, (float4*)out_ea, n4);
}

// Round 3
// 704.113 us; speedup vs baseline: 1.8348x; 1.0681x over previous
//
#include <hip/hip_runtime.h>
#include <cstdio>
#include <cstdint>

#define LRELU 0.2f
#define BN_EPS 1e-5f

typedef short bf16x8 __attribute__((ext_vector_type(8)));
typedef float f32x4 __attribute__((ext_vector_type(4)));

__device__ inline unsigned short f2bf(float f) {
  unsigned int u = __float_as_uint(f);
  u += 0x7fffu + ((u >> 16) & 1u);   // RNE
  return (unsigned short)(u >> 16);
}
__device__ inline float bf2f(unsigned short v) {
  return __uint_as_float(((unsigned int)v) << 16);
}

// =========== CSR build (bucketed: bucket = dst>>8, NB = ceil(N/256)) ========

// degree histogram + LDS-staged bucket histogram in one pass over dst
__global__ __launch_bounds__(256) void k_deg_bhist(const int* __restrict__ dst,
                                                   int* __restrict__ deg,
                                                   int* __restrict__ bh, int E) {
  __shared__ int cnt[512];
  for (int b = threadIdx.x; b < 512; b += 256) cnt[b] = 0;
  __syncthreads();
  for (int i = blockIdx.x * blockDim.x + threadIdx.x; i < E;
       i += gridDim.x * blockDim.x) {
    int d = dst[i];
    atomicAdd(&deg[d], 1);
    atomicAdd(&cnt[d >> 8], 1);
  }
  __syncthreads();
  for (int b = threadIdx.x; b < 512; b += 256)
    if (cnt[b]) atomicAdd(&bh[b], cnt[b]);
}

// per-256-tile exclusive scan of deg (tile-local)
__global__ void k_scan_tile(const int* __restrict__ deg, int* __restrict__ offs,
                            int* __restrict__ tilesum, int N) {
  __shared__ int sh[256];
  int i = blockIdx.x * 256 + threadIdx.x;
  int v = (i < N) ? deg[i] : 0;
  sh[threadIdx.x] = v;
  __syncthreads();
  for (int s = 1; s < 256; s <<= 1) {
    int t = (threadIdx.x >= s) ? sh[threadIdx.x - s] : 0;
    __syncthreads();
    sh[threadIdx.x] += t;
    __syncthreads();
  }
  if (i < N) offs[i] = sh[threadIdx.x] - v;
  if (threadIdx.x == 255) tilesum[blockIdx.x] = sh[255];
}

// parallel exclusive scan of up to 512 values (1 block, 512 threads)
__global__ __launch_bounds__(512) void k_exscan(const int* __restrict__ in,
                                                int* __restrict__ pre, int n,
                                                int* __restrict__ totalp,
                                                int* __restrict__ copyto) {
  __shared__ int sh[512];
  int v = (threadIdx.x < n) ? in[threadIdx.x] : 0;
  sh[threadIdx.x] = v;
  __syncthreads();
  for (int s = 1; s < 512; s <<= 1) {
    int t = (threadIdx.x >= s) ? sh[threadIdx.x - s] : 0;
    __syncthreads();
    sh[threadIdx.x] += t;
    __syncthreads();
  }
  int ex = sh[threadIdx.x] - v;
  if (threadIdx.x < n) {
    pre[threadIdx.x] = ex;
    if (copyto) copyto[threadIdx.x] = ex;
  }
  if ((int)threadIdx.x == n - 1 && totalp) *totalp = sh[threadIdx.x];
}

__global__ void k_addfix(int* __restrict__ offs, const int* __restrict__ tilepre,
                         int N) {
  int i = blockIdx.x * blockDim.x + threadIdx.x;
  if (i < N) offs[i] += tilepre[i >> 8];
}

// bucket the edges: dense per-(block,bucket) chunks -> full-line writes
__global__ __launch_bounds__(256) void k_bscatter(const int* __restrict__ src,
                                                  const int* __restrict__ dst,
                                                  int* __restrict__ bcur,
                                                  uint2* __restrict__ bpair, int E) {
  __shared__ int cnt[512];
  const int chunk = (E + gridDim.x - 1) / gridDim.x;
  const int beg = blockIdx.x * chunk;
  const int end = min(E, beg + chunk);
  for (int b = threadIdx.x; b < 512; b += 256) cnt[b] = 0;
  __syncthreads();
  for (int e = beg + threadIdx.x; e < end; e += 256)
    atomicAdd(&cnt[dst[e] >> 8], 1);
  __syncthreads();
  for (int b = threadIdx.x; b < 512; b += 256) {
    int c = cnt[b];
    cnt[b] = (c > 0) ? atomicAdd(&bcur[b], c) : 0;  // claim dense range
  }
  __syncthreads();
  for (int e = beg + threadIdx.x; e < end; e += 256) {
    int d = dst[e];
    int pos = atomicAdd(&cnt[d >> 8], 1);           // LDS cursor
    bpair[pos] = make_uint2((unsigned)src[e], (unsigned)d);
  }
}

// one block per bucket: scatter into contiguous CSR span (L2-hot, ~16KB)
__global__ __launch_bounds__(256) void k_bcsr(const uint2* __restrict__ bpair,
                                              const int* __restrict__ bstart,
                                              const int* __restrict__ offs,
                                              int* __restrict__ srcs, int N) {
  __shared__ int cur[256];
  const int b = blockIdx.x;
  const int lo = b << 8;
  if (lo + (int)threadIdx.x < N) cur[threadIdx.x] = offs[lo + threadIdx.x];
  __syncthreads();
  const int e0 = bstart[b], e1 = bstart[b + 1];
  for (int e = e0 + threadIdx.x; e < e1; e += 256) {
    uint2 p = bpair[e];
    int pos = atomicAdd(&cur[p.y & 255], 1);
    srcs[pos] = (int)p.x;
  }
}

// ====== weight cast+transpose: W[K][128] f32 -> Wt[128][K] bf16 =============
template <int K>
__global__ void k_castW(const float* __restrict__ W, unsigned short* __restrict__ Wt) {
  int o = blockIdx.x * blockDim.x + threadIdx.x;
  if (o < 128 * K) {
    int n = o / K, k = o - n * K;
    Wt[o] = f2bf(W[k * 128 + n]);
  }
}

// ====== MFMA GEMM + fused attention logits (+ optional fused BN+ReLU) =======
// A: [N,K] fp32 (BN: x*sc[c]+sh[c], relu).  Wt: [128][K] bf16.
// out: h [N,128] bf16, als/ald [N,4] fp32.
// A-frag: A[m=lane&15][k=quad*8+j]; B-frag dual; C/D: col=lane&15,row=quad*4+reg
template <int K, bool BN>
__global__ __launch_bounds__(256) void k_mfma(
    const float* __restrict__ Ain, const unsigned short* __restrict__ Wt,
    const float* __restrict__ asrc, const float* __restrict__ adst,
    const float* __restrict__ bnsc, const float* __restrict__ bnsh,
    unsigned short* __restrict__ h, float* __restrict__ als,
    float* __restrict__ ald, int N) {
  __shared__ unsigned short lsh[4][16 * 132];
  const int wv   = threadIdx.x >> 6;
  const int lane = threadIdx.x & 63;
  const int quad = lane >> 4;
  const int col  = lane & 15;
  const int m0   = blockIdx.x * 64 + wv * 16;
  const int rowc = min(m0 + col, N - 1);

  f32x4 acc[8];
#pragma unroll
  for (int t = 0; t < 8; t++) acc[t] = (f32x4){0.f, 0.f, 0.f, 0.f};

#pragma unroll
  for (int ks = 0; ks < K / 32; ks++) {
    const int k0 = ks * 32 + quad * 8;
    const float* ap = Ain + (size_t)rowc * K + k0;
    float4 f0 = *(const float4*)ap;
    float4 f1 = *(const float4*)(ap + 4);
    bf16x8 a;
    if constexpr (BN) {
      f0.x = fmaxf(0.f, fmaf(f0.x, bnsc[k0 + 0], bnsh[k0 + 0]));
      f0.y = fmaxf(0.f, fmaf(f0.y, bnsc[k0 + 1], bnsh[k0 + 1]));
      f0.z = fmaxf(0.f, fmaf(f0.z, bnsc[k0 + 2], bnsh[k0 + 2]));
      f0.w = fmaxf(0.f, fmaf(f0.w, bnsc[k0 + 3], bnsh[k0 + 3]));
      f1.x = fmaxf(0.f, fmaf(f1.x, bnsc[k0 + 4], bnsh[k0 + 4]));
      f1.y = fmaxf(0.f, fmaf(f1.y, bnsc[k0 + 5], bnsh[k0 + 5]));
      f1.z = fmaxf(0.f, fmaf(f1.z, bnsc[k0 + 6], bnsh[k0 + 6]));
      f1.w = fmaxf(0.f, fmaf(f1.w, bnsc[k0 + 7], bnsh[k0 + 7]));
    }
    a[0] = (short)f2bf(f0.x); a[1] = (short)f2bf(f0.y);
    a[2] = (short)f2bf(f0.z); a[3] = (short)f2bf(f0.w);
    a[4] = (short)f2bf(f1.x); a[5] = (short)f2bf(f1.y);
    a[6] = (short)f2bf(f1.z); a[7] = (short)f2bf(f1.w);
#pragma unroll
    for (int t = 0; t < 8; t++) {
      bf16x8 b = *(const bf16x8*)(Wt + (size_t)(t * 16 + col) * K + k0);
      acc[t] = __builtin_amdgcn_mfma_f32_16x16x32_bf16(a, b, acc[t], 0, 0, 0);
    }
  }

#pragma unroll
  for (int t = 0; t < 8; t++) {
#pragma unroll
    for (int j = 0; j < 4; j++)
      lsh[wv][(quad * 4 + j) * 132 + col + 16 * t] = f2bf(acc[t][j]);
  }
  __syncthreads();

  float as8[8], ad8[8];
#pragma unroll
  for (int j = 0; j < 8; j++) {
    as8[j] = asrc[col * 8 + j];
    ad8[j] = adst[col * 8 + j];
  }

#pragma unroll
  for (int i = 0; i < 4; i++) {
    const int row = i * 4 + quad;
    const int hrow = m0 + row;
    const unsigned short* rp = &lsh[wv][row * 132 + col * 8];
    ushort4 lo = *(const ushort4*)rp;
    ushort4 hi = *(const ushort4*)(rp + 4);
    float p = 0.f, q = 0.f, v;
    v = bf2f(lo.x); p += v * as8[0]; q += v * ad8[0];
    v = bf2f(lo.y); p += v * as8[1]; q += v * ad8[1];
    v = bf2f(lo.z); p += v * as8[2]; q += v * ad8[2];
    v = bf2f(lo.w); p += v * as8[3]; q += v * ad8[3];
    v = bf2f(hi.x); p += v * as8[4]; q += v * ad8[4];
    v = bf2f(hi.y); p += v * as8[5]; q += v * ad8[5];
    v = bf2f(hi.z); p += v * as8[6]; q += v * ad8[6];
    v = bf2f(hi.w); p += v * as8[7]; q += v * ad8[7];
    if (hrow < N) {
      ushort4* gp = (ushort4*)(h + (size_t)hrow * 128 + col * 8);
      gp[0] = lo; gp[1] = hi;
    }
    p += __shfl_xor(p, 1); p += __shfl_xor(p, 2);
    q += __shfl_xor(q, 1); q += __shfl_xor(q, 2);
    if ((lane & 3) == 0 && hrow < N) {
      const int head = col >> 2;
      als[hrow * 4 + head] = p;
      ald[hrow * 4 + head] = q;
    }
  }
}

// ====== per-dst aggregation: one wave/node, 8 gathers in flight =============
__global__ __launch_bounds__(256) void k_agg(
    const unsigned int* __restrict__ h2, const float* __restrict__ als,
    const float* __restrict__ ald, const int* __restrict__ offs,
    const int* __restrict__ srcs, const float* __restrict__ bias,
    float* __restrict__ y, int N) {
  int node = blockIdx.x * 4 + (threadIdx.x >> 6);
  if (node >= N) return;
  int lane = threadIdx.x & 63;   // lane owns channels 2*lane, 2*lane+1
  int head = lane >> 4;
  float ad = ald[node * 4 + head];
  int beg = offs[node], end = offs[node + 1];
  float ax0 = 0.f, ay0 = 0.f, dn0 = 0.f;
  float ax1 = 0.f, ay1 = 0.f, dn1 = 0.f;
  int e = beg;
  for (; e + 8 <= end; e += 8) {
    int s[8];
#pragma unroll
    for (int j = 0; j < 8; j++) s[j] = srcs[e + j];
    float aa[8];
    unsigned int u[8];
#pragma unroll
    for (int j = 0; j < 8; j++) aa[j] = als[s[j] * 4 + head];
#pragma unroll
    for (int j = 0; j < 8; j++) u[j] = h2[s[j] * 64 + lane];
#pragma unroll
    for (int j = 0; j < 8; j++) {
      float ev = aa[j] + ad;
      ev = (ev >= 0.f) ? ev : LRELU * ev;
      float w = __expf(ev);
      if (j & 1) {
        dn1 += w;
        ax1 = fmaf(w, __uint_as_float(u[j] << 16), ax1);
        ay1 = fmaf(w, __uint_as_float(u[j] & 0xffff0000u), ay1);
      } else {
        dn0 += w;
        ax0 = fmaf(w, __uint_as_float(u[j] << 16), ax0);
        ay0 = fmaf(w, __uint_as_float(u[j] & 0xffff0000u), ay0);
      }
    }
  }
  for (; e < end; e++) {
    int s = srcs[e];
    float as = als[s * 4 + head];
    float ev = as + ad;
    ev = (ev >= 0.f) ? ev : LRELU * ev;
    float w = __expf(ev);
    unsigned int u = h2[s * 64 + lane];
    dn0 += w;
    ax0 = fmaf(w, __uint_as_float(u << 16), ax0);
    ay0 = fmaf(w, __uint_as_float(u & 0xffff0000u), ay0);
  }
  float den = dn0 + dn1;
  float ax = ax0 + ax1, ay = ay0 + ay1;
  float r = (den > 0.f) ? (1.f / den) : 0.f;
  ax *= r; ay *= r;
  ax += __shfl_xor(ax, 16); ay += __shfl_xor(ay, 16);
  ax += __shfl_xor(ax, 32); ay += __shfl_xor(ay, 32);
  if (lane < 16) {
    float2 b2 = ((const float2*)bias)[lane];
    float2 o;
    o.x = 0.25f * ax + b2.x;
    o.y = 0.25f * ay + b2.y;
    ((float2*)(y + (size_t)node * 32))[lane] = o;
  }
}

// ---------------- batch norm ----------------
__global__ __launch_bounds__(256) void k_bnstats(const float* __restrict__ y,
                                                 float* __restrict__ stats, int N) {
  __shared__ float s1[32], s2[32];
  if (threadIdx.x < 32) { s1[threadIdx.x] = 0.f; s2[threadIdx.x] = 0.f; }
  __syncthreads();
  float a = 0.f, b = 0.f;
  int total = N * 32;
  for (int i = blockIdx.x * blockDim.x + threadIdx.x; i < total;
       i += gridDim.x * blockDim.x) {
    float v = y[i];
    a += v; b += v * v;
  }
  int c = threadIdx.x & 31;
  atomicAdd(&s1[c], a); atomicAdd(&s2[c], b);
  __syncthreads();
  if (threadIdx.x < 32) {
    atomicAdd(&stats[threadIdx.x], s1[threadIdx.x]);
    atomicAdd(&stats[32 + threadIdx.x], s2[threadIdx.x]);
  }
}

__global__ void k_bnfinal(const float* __restrict__ stats, const float* __restrict__ g,
                          const float* __restrict__ be, float* __restrict__ sc,
                          float* __restrict__ sh, int N) {
  int c = threadIdx.x;
  if (c < 32) {
    float inv = 1.f / (float)N;
    float mu = stats[c] * inv;
    float var = stats[32 + c] * inv - mu * mu;   // biased, as in ref
    float s = g[c] * rsqrtf(var + BN_EPS);
    sc[c] = s;
    sh[c] = be[c] - mu * s;
  }
}

__global__ void k_copy4(const float4* __restrict__ s, float4* __restrict__ d, int n) {
  int i = blockIdx.x * blockDim.x + threadIdx.x;
  if (i < n) d[i] = s[i];
}

// ---------------- launch ----------------
extern "C" void kernel_launch(void* const* d_in, const int* in_sizes, int n_in,
                              void* d_out, int out_size, void* d_ws, size_t ws_size,
                              hipStream_t stream) {
  const float* x   = (const float*)d_in[0];
  const int*   ei  = (const int*)d_in[1];
  const float* ea  = (const float*)d_in[2];
  const float* W0  = (const float*)d_in[3];
  const float* as0 = (const float*)d_in[4];
  const float* ad0 = (const float*)d_in[5];
  const float* b0  = (const float*)d_in[6];
  const float* g0  = (const float*)d_in[7];
  const float* be0 = (const float*)d_in[8];
  const float* W1  = (const float*)d_in[9];
  const float* as1 = (const float*)d_in[10];
  const float* ad1 = (const float*)d_in[11];
  const float* b1  = (const float*)d_in[12];
  const float* g1  = (const float*)d_in[13];
  const float* be1 = (const float*)d_in[14];
  const float* W2  = (const float*)d_in[15];
  const float* as2 = (const float*)d_in[16];
  const float* ad2 = (const float*)d_in[17];
  const float* b2  = (const float*)d_in[18];

  const int N = in_sizes[0] / 128;
  const int E = in_sizes[1] / 2;
  const int* srcI = ei;
  const int* dstI = ei + E;
  const int NB = (N + 255) >> 8;       // buckets (<=512 for N<=131072)
  const int nb = (N + 255) / 256;      // scan tiles (== NB)

  char* w = (char*)d_ws;
  auto carve = [&](size_t bytes) -> void* {
    void* p = (void*)w;
    w += (bytes + 255) & ~(size_t)255;
    return p;
  };
  unsigned short* h  = (unsigned short*)carve((size_t)N * 128 * 2);
  float* als        = (float*)carve((size_t)N * 4 * 4);
  float* ald        = (float*)carve((size_t)N * 4 * 4);
  float* y          = (float*)carve((size_t)N * 32 * 4);
  int* offs         = (int*)carve((size_t)(N + 1) * 4);
  int* srcs         = (int*)carve((size_t)E * 4);
  int* deg          = (int*)carve((size_t)N * 4);
  int* tilesum      = (int*)carve((size_t)nb * 4);
  int* tilepre      = (int*)carve((size_t)nb * 4);
  int* bh           = (int*)carve(512 * 4);
  int* bstart       = (int*)carve(513 * 4);
  int* bcur         = (int*)carve(512 * 4);
  float* stats      = (float*)carve(128 * 4);
  float* bnsc       = (float*)carve(32 * 4);
  float* bnsh       = (float*)carve(32 * 4);
  unsigned short* Wt0 = (unsigned short*)carve(128 * 128 * 2);
  unsigned short* Wt1 = (unsigned short*)carve(128 * 32 * 2);
  unsigned short* Wt2 = (unsigned short*)carve(128 * 32 * 2);
  if ((size_t)(w - (char*)d_ws) > ws_size) {
    fprintf(stderr, "GAT kernel: ws too small (%zu needed, %zu given)\n",
            (size_t)(w - (char*)d_ws), ws_size);
    return;
  }
  // bpair aliases h: consumed by k_bcsr before k_mfma writes h (same stream)
  uint2* bpair = (uint2*)h;

  hipMemsetAsync(deg, 0, (size_t)N * 4, stream);
  hipMemsetAsync(bh, 0, 512 * 4, stream);
  hipMemsetAsync(stats, 0, 128 * 4, stream);

  k_deg_bhist<<<256, 256, 0, stream>>>(dstI, deg, bh, E);
  k_scan_tile<<<nb, 256, 0, stream>>>(deg, offs, tilesum, N);
  k_exscan<<<1, 512, 0, stream>>>(tilesum, tilepre, nb, offs + N, nullptr);
  k_addfix<<<(N + 255) / 256, 256, 0, stream>>>(offs, tilepre, N);
  k_exscan<<<1, 512, 0, stream>>>(bh, bstart, NB, bstart + NB, bcur);
  k_bscatter<<<128, 256, 0, stream>>>(srcI, dstI, bcur, bpair, E);
  k_bcsr<<<NB, 256, 0, stream>>>(bpair, bstart, offs, srcs, N);

  k_castW<128><<<64, 256, 0, stream>>>(W0, Wt0);
  k_castW<32><<<16, 256, 0, stream>>>(W1, Wt1);
  k_castW<32><<<16, 256, 0, stream>>>(W2, Wt2);

  const int gGemm = (N + 63) / 64;
  const int gAgg  = (N + 3) / 4;
  float* out_nodes = (float*)d_out;
  float* out_ea    = out_nodes + (size_t)N * 32;

  // layer 0
  k_mfma<128, false><<<gGemm, 256, 0, stream>>>(x, Wt0, as0, ad0, nullptr, nullptr,
                                                h, als, ald, N);
  k_agg<<<gAgg, 256, 0, stream>>>((const unsigned int*)h, als, ald, offs, srcs, b0, y, N);
  k_bnstats<<<512, 256, 0, stream>>>(y, stats, N);
  k_bnfinal<<<1, 32, 0, stream>>>(stats, g0, be0, bnsc, bnsh, N);
  // layer 1 (BN+ReLU fused into GEMM A-load)
  k_mfma<32, true><<<gGemm, 256, 0, stream>>>(y, Wt1, as1, ad1, bnsc, bnsh,
                                              h, als, ald, N);
  k_agg<<<gAgg, 256, 0, stream>>>((const unsigned int*)h, als, ald, offs, srcs, b1, y, N);
  k_bnstats<<<512, 256, 0, stream>>>(y, stats + 64, N);
  k_bnfinal<<<1, 32, 0, stream>>>(stats + 64, g1, be1, bnsc, bnsh, N);
  // layer 2 (writes node output directly to d_out)
  k_mfma<32, true><<<gGemm, 256, 0, stream>>>(y, Wt2, as2, ad2, bnsc, bnsh,
                                              h, als, ald, N);
  k_agg<<<gAgg, 256, 0, stream>>>((const unsigned int*)h, als, ald, offs, srcs, b2,
                                  out_nodes, N);
  // edge_attr passthrough
  const int n4 = E * 2;
  k_copy4<<<(n4 + 255) / 256, 256, 0, stream>>>((const float4*)ea, (float4*)out_ea, n4);
}

// Round 4
// 655.233 us; speedup vs baseline: 1.9717x; 1.0746x over previous
//
#include <hip/hip_runtime.h>
#include <cstdio>
#include <cstdint>

#define LRELU 0.2f
#define BN_EPS 1e-5f

typedef short bf16x8 __attribute__((ext_vector_type(8)));
typedef float f32x4 __attribute__((ext_vector_type(4)));

__device__ inline unsigned short f2bf(float f) {
  unsigned int u = __float_as_uint(f);
  u += 0x7fffu + ((u >> 16) & 1u);   // RNE
  return (unsigned short)(u >> 16);
}
__device__ inline float bf2f(unsigned short v) {
  return __uint_as_float(((unsigned int)v) << 16);
}

// =========== CSR build (bucketed: bucket = dst>>8, NB = ceil(N/256)) ========

__global__ __launch_bounds__(256) void k_deg_bhist(const int* __restrict__ dst,
                                                   int* __restrict__ deg,
                                                   int* __restrict__ bh, int E) {
  __shared__ int cnt[512];
  for (int b = threadIdx.x; b < 512; b += 256) cnt[b] = 0;
  __syncthreads();
  for (int i = blockIdx.x * blockDim.x + threadIdx.x; i < E;
       i += gridDim.x * blockDim.x) {
    int d = dst[i];
    atomicAdd(&deg[d], 1);
    atomicAdd(&cnt[d >> 8], 1);
  }
  __syncthreads();
  for (int b = threadIdx.x; b < 512; b += 256)
    if (cnt[b]) atomicAdd(&bh[b], cnt[b]);
}

__global__ void k_scan_tile(const int* __restrict__ deg, int* __restrict__ offs,
                            int* __restrict__ tilesum, int N) {
  __shared__ int sh[256];
  int i = blockIdx.x * 256 + threadIdx.x;
  int v = (i < N) ? deg[i] : 0;
  sh[threadIdx.x] = v;
  __syncthreads();
  for (int s = 1; s < 256; s <<= 1) {
    int t = (threadIdx.x >= s) ? sh[threadIdx.x - s] : 0;
    __syncthreads();
    sh[threadIdx.x] += t;
    __syncthreads();
  }
  if (i < N) offs[i] = sh[threadIdx.x] - v;
  if (threadIdx.x == 255) tilesum[blockIdx.x] = sh[255];
}

// both 391-long scans in one launch: tilesum->tilepre (+E total) and
// bh->bstart (+copy to bcur)
__global__ __launch_bounds__(512) void k_exscan2(
    const int* __restrict__ tilesum, int* __restrict__ tilepre,
    const int* __restrict__ bh, int* __restrict__ bstart,
    int* __restrict__ bcur, int n, int* __restrict__ etot) {
  __shared__ int sh[512];
  const int t = threadIdx.x;
  int v = (t < n) ? tilesum[t] : 0;
  sh[t] = v;
  __syncthreads();
  for (int s = 1; s < 512; s <<= 1) {
    int u = (t >= s) ? sh[t - s] : 0;
    __syncthreads();
    sh[t] += u;
    __syncthreads();
  }
  if (t < n) tilepre[t] = sh[t] - v;
  if (t == n - 1) *etot = sh[t];
  __syncthreads();
  int v2 = (t < n) ? bh[t] : 0;
  sh[t] = v2;
  __syncthreads();
  for (int s = 1; s < 512; s <<= 1) {
    int u = (t >= s) ? sh[t - s] : 0;
    __syncthreads();
    sh[t] += u;
    __syncthreads();
  }
  if (t < n) {
    int ex = sh[t] - v2;
    bstart[t] = ex;
    bcur[t] = ex;
  }
  if (t == n - 1) bstart[n] = sh[t];
}

__global__ void k_addfix(int* __restrict__ offs, const int* __restrict__ tilepre,
                         int N) {
  int i = blockIdx.x * blockDim.x + threadIdx.x;
  if (i < N) offs[i] += tilepre[i >> 8];
}

__global__ __launch_bounds__(256) void k_bscatter(const int* __restrict__ src,
                                                  const int* __restrict__ dst,
                                                  int* __restrict__ bcur,
                                                  uint2* __restrict__ bpair, int E) {
  __shared__ int cnt[512];
  const int chunk = (E + gridDim.x - 1) / gridDim.x;
  const int beg = blockIdx.x * chunk;
  const int end = min(E, beg + chunk);
  for (int b = threadIdx.x; b < 512; b += 256) cnt[b] = 0;
  __syncthreads();
  for (int e = beg + threadIdx.x; e < end; e += 256)
    atomicAdd(&cnt[dst[e] >> 8], 1);
  __syncthreads();
  for (int b = threadIdx.x; b < 512; b += 256) {
    int c = cnt[b];
    cnt[b] = (c > 0) ? atomicAdd(&bcur[b], c) : 0;
  }
  __syncthreads();
  for (int e = beg + threadIdx.x; e < end; e += 256) {
    int d = dst[e];
    int pos = atomicAdd(&cnt[d >> 8], 1);
    bpair[pos] = make_uint2((unsigned)src[e], (unsigned)d);
  }
}

__global__ __launch_bounds__(256) void k_bcsr(const uint2* __restrict__ bpair,
                                              const int* __restrict__ bstart,
                                              const int* __restrict__ offs,
                                              int* __restrict__ srcs, int N) {
  __shared__ int cur[256];
  const int b = blockIdx.x;
  const int lo = b << 8;
  if (lo + (int)threadIdx.x < N) cur[threadIdx.x] = offs[lo + threadIdx.x];
  __syncthreads();
  const int e0 = bstart[b], e1 = bstart[b + 1];
  for (int e = e0 + threadIdx.x; e < e1; e += 256) {
    uint2 p = bpair[e];
    int pos = atomicAdd(&cur[p.y & 255], 1);
    srcs[pos] = (int)p.x;
  }
}

// ====== weight cast+transpose (all 3 layers, one launch) ====================
__global__ void k_castW3(const float* __restrict__ W0, const float* __restrict__ W1,
                         const float* __restrict__ W2,
                         unsigned short* __restrict__ Wt0,
                         unsigned short* __restrict__ Wt1,
                         unsigned short* __restrict__ Wt2) {
  int o = blockIdx.x * 256 + threadIdx.x;   // 16384 + 4096 + 4096 = 24576
  if (o < 16384) {
    int n = o >> 7, k = o & 127;
    Wt0[o] = f2bf(W0[k * 128 + n]);
  } else if (o < 20480) {
    int p = o - 16384, n = p >> 5, k = p & 31;
    Wt1[p] = f2bf(W1[k * 128 + n]);
  } else if (o < 24576) {
    int p = o - 20480, n = p >> 5, k = p & 31;
    Wt2[p] = f2bf(W2[k * 128 + n]);
  }
}

// ====== MFMA GEMM + fused attention logits (+ optional fused BN+ReLU) =======
template <int K, bool BN>
__global__ __launch_bounds__(256) void k_mfma(
    const float* __restrict__ Ain, const unsigned short* __restrict__ Wt,
    const float* __restrict__ asrc, const float* __restrict__ adst,
    const float* __restrict__ bnsc, const float* __restrict__ bnsh,
    unsigned short* __restrict__ h, float* __restrict__ als,
    float* __restrict__ ald, int N) {
  __shared__ unsigned short lsh[4][16 * 132];
  const int wv   = threadIdx.x >> 6;
  const int lane = threadIdx.x & 63;
  const int quad = lane >> 4;
  const int col  = lane & 15;
  const int m0   = blockIdx.x * 64 + wv * 16;
  const int rowc = min(m0 + col, N - 1);

  f32x4 acc[8];
#pragma unroll
  for (int t = 0; t < 8; t++) acc[t] = (f32x4){0.f, 0.f, 0.f, 0.f};

#pragma unroll
  for (int ks = 0; ks < K / 32; ks++) {
    const int k0 = ks * 32 + quad * 8;
    const float* ap = Ain + (size_t)rowc * K + k0;
    float4 f0 = *(const float4*)ap;
    float4 f1 = *(const float4*)(ap + 4);
    bf16x8 a;
    if constexpr (BN) {
      f0.x = fmaxf(0.f, fmaf(f0.x, bnsc[k0 + 0], bnsh[k0 + 0]));
      f0.y = fmaxf(0.f, fmaf(f0.y, bnsc[k0 + 1], bnsh[k0 + 1]));
      f0.z = fmaxf(0.f, fmaf(f0.z, bnsc[k0 + 2], bnsh[k0 + 2]));
      f0.w = fmaxf(0.f, fmaf(f0.w, bnsc[k0 + 3], bnsh[k0 + 3]));
      f1.x = fmaxf(0.f, fmaf(f1.x, bnsc[k0 + 4], bnsh[k0 + 4]));
      f1.y = fmaxf(0.f, fmaf(f1.y, bnsc[k0 + 5], bnsh[k0 + 5]));
      f1.z = fmaxf(0.f, fmaf(f1.z, bnsc[k0 + 6], bnsh[k0 + 6]));
      f1.w = fmaxf(0.f, fmaf(f1.w, bnsc[k0 + 7], bnsh[k0 + 7]));
    }
    a[0] = (short)f2bf(f0.x); a[1] = (short)f2bf(f0.y);
    a[2] = (short)f2bf(f0.z); a[3] = (short)f2bf(f0.w);
    a[4] = (short)f2bf(f1.x); a[5] = (short)f2bf(f1.y);
    a[6] = (short)f2bf(f1.z); a[7] = (short)f2bf(f1.w);
#pragma unroll
    for (int t = 0; t < 8; t++) {
      bf16x8 b = *(const bf16x8*)(Wt + (size_t)(t * 16 + col) * K + k0);
      acc[t] = __builtin_amdgcn_mfma_f32_16x16x32_bf16(a, b, acc[t], 0, 0, 0);
    }
  }

#pragma unroll
  for (int t = 0; t < 8; t++) {
#pragma unroll
    for (int j = 0; j < 4; j++)
      lsh[wv][(quad * 4 + j) * 132 + col + 16 * t] = f2bf(acc[t][j]);
  }
  __syncthreads();

  float as8[8], ad8[8];
#pragma unroll
  for (int j = 0; j < 8; j++) {
    as8[j] = asrc[col * 8 + j];
    ad8[j] = adst[col * 8 + j];
  }

#pragma unroll
  for (int i = 0; i < 4; i++) {
    const int row = i * 4 + quad;
    const int hrow = m0 + row;
    const unsigned short* rp = &lsh[wv][row * 132 + col * 8];
    ushort4 lo = *(const ushort4*)rp;
    ushort4 hi = *(const ushort4*)(rp + 4);
    float p = 0.f, q = 0.f, v;
    v = bf2f(lo.x); p += v * as8[0]; q += v * ad8[0];
    v = bf2f(lo.y); p += v * as8[1]; q += v * ad8[1];
    v = bf2f(lo.z); p += v * as8[2]; q += v * ad8[2];
    v = bf2f(lo.w); p += v * as8[3]; q += v * ad8[3];
    v = bf2f(hi.x); p += v * as8[4]; q += v * ad8[4];
    v = bf2f(hi.y); p += v * as8[5]; q += v * ad8[5];
    v = bf2f(hi.z); p += v * as8[6]; q += v * ad8[6];
    v = bf2f(hi.w); p += v * as8[7]; q += v * ad8[7];
    if (hrow < N) {
      ushort4* gp = (ushort4*)(h + (size_t)hrow * 128 + col * 8);
      gp[0] = lo; gp[1] = hi;
    }
    p += __shfl_xor(p, 1); p += __shfl_xor(p, 2);
    q += __shfl_xor(q, 1); q += __shfl_xor(q, 2);
    if ((lane & 3) == 0 && hrow < N) {
      const int head = col >> 2;
      als[hrow * 4 + head] = p;
      ald[hrow * 4 + head] = q;
    }
  }
}

// ====== per-dst aggregation: scalar-addressed gathers =======================
// srcs[e] is wave-uniform -> readlane to SGPR: gather address math goes to
// SALU, loads become saddr+const-voffset, zero per-lane VALU addressing.
__global__ __launch_bounds__(256) void k_agg(
    const unsigned int* __restrict__ h2, const float* __restrict__ als,
    const float* __restrict__ ald, const int* __restrict__ offs,
    const int* __restrict__ srcs, const float* __restrict__ bias,
    float* __restrict__ y, int N) {
  const int node = blockIdx.x * 4 + (threadIdx.x >> 6);
  if (node >= N) return;
  const int lane = threadIdx.x & 63;   // lane owns channels 2*lane, 2*lane+1
  const int head = lane >> 4;
  const int beg = __builtin_amdgcn_readfirstlane(offs[node]);
  const int end = __builtin_amdgcn_readfirstlane(offs[node + 1]);
  const float ad = ald[node * 4 + head];
  float ax = 0.f, ay = 0.f, dn = 0.f;

  for (int base = beg; base < end; base += 64) {
    const int m = min(64, end - base);
    // one coalesced load covers up to 64 edges' src indices
    const int sv = srcs[base + min(lane, m - 1)];
    int j = 0;
    for (; j + 4 <= m; j += 4) {
      const int s0 = __builtin_amdgcn_readlane(sv, j + 0);
      const int s1 = __builtin_amdgcn_readlane(sv, j + 1);
      const int s2 = __builtin_amdgcn_readlane(sv, j + 2);
      const int s3 = __builtin_amdgcn_readlane(sv, j + 3);
      const float a0 = als[s0 * 4 + head];
      const float a1 = als[s1 * 4 + head];
      const float a2 = als[s2 * 4 + head];
      const float a3 = als[s3 * 4 + head];
      const unsigned int u0 = h2[(size_t)s0 * 64 + lane];
      const unsigned int u1 = h2[(size_t)s1 * 64 + lane];
      const unsigned int u2 = h2[(size_t)s2 * 64 + lane];
      const unsigned int u3 = h2[(size_t)s3 * 64 + lane];
      float e0 = a0 + ad; e0 = fmaxf(e0, LRELU * e0);
      float e1 = a1 + ad; e1 = fmaxf(e1, LRELU * e1);
      float e2 = a2 + ad; e2 = fmaxf(e2, LRELU * e2);
      float e3 = a3 + ad; e3 = fmaxf(e3, LRELU * e3);
      const float w0 = __expf(e0), w1 = __expf(e1);
      const float w2 = __expf(e2), w3 = __expf(e3);
      dn += w0 + w1 + w2 + w3;
      ax = fmaf(w0, __uint_as_float(u0 << 16), ax);
      ay = fmaf(w0, __uint_as_float(u0 & 0xffff0000u), ay);
      ax = fmaf(w1, __uint_as_float(u1 << 16), ax);
      ay = fmaf(w1, __uint_as_float(u1 & 0xffff0000u), ay);
      ax = fmaf(w2, __uint_as_float(u2 << 16), ax);
      ay = fmaf(w2, __uint_as_float(u2 & 0xffff0000u), ay);
      ax = fmaf(w3, __uint_as_float(u3 << 16), ax);
      ay = fmaf(w3, __uint_as_float(u3 & 0xffff0000u), ay);
    }
    for (; j < m; j++) {
      const int s = __builtin_amdgcn_readlane(sv, j);
      const float a = als[s * 4 + head];
      const unsigned int u = h2[(size_t)s * 64 + lane];
      float ev = a + ad;
      ev = fmaxf(ev, LRELU * ev);
      const float w = __expf(ev);
      dn += w;
      ax = fmaf(w, __uint_as_float(u << 16), ax);
      ay = fmaf(w, __uint_as_float(u & 0xffff0000u), ay);
    }
  }

  const float r = (dn > 0.f) ? (1.f / dn) : 0.f;
  ax *= r; ay *= r;
  ax += __shfl_xor(ax, 16); ay += __shfl_xor(ay, 16);
  ax += __shfl_xor(ax, 32); ay += __shfl_xor(ay, 32);
  if (lane < 16) {
    float2 b2 = ((const float2*)bias)[lane];
    float2 o;
    o.x = 0.25f * ax + b2.x;
    o.y = 0.25f * ay + b2.y;
    ((float2*)(y + (size_t)node * 32))[lane] = o;
  }
}

// ---------------- batch norm ----------------
__global__ __launch_bounds__(256) void k_bnstats(const float* __restrict__ y,
                                                 float* __restrict__ stats, int N) {
  __shared__ float s1[32], s2[32];
  if (threadIdx.x < 32) { s1[threadIdx.x] = 0.f; s2[threadIdx.x] = 0.f; }
  __syncthreads();
  float a = 0.f, b = 0.f;
  int total = N * 32;
  for (int i = blockIdx.x * blockDim.x + threadIdx.x; i < total;
       i += gridDim.x * blockDim.x) {
    float v = y[i];
    a += v; b += v * v;
  }
  int c = threadIdx.x & 31;
  atomicAdd(&s1[c], a); atomicAdd(&s2[c], b);
  __syncthreads();
  if (threadIdx.x < 32) {
    atomicAdd(&stats[threadIdx.x], s1[threadIdx.x]);
    atomicAdd(&stats[32 + threadIdx.x], s2[threadIdx.x]);
  }
}

__global__ void k_bnfinal(const float* __restrict__ stats, const float* __restrict__ g,
                          const float* __restrict__ be, float* __restrict__ sc,
                          float* __restrict__ sh, int N) {
  int c = threadIdx.x;
  if (c < 32) {
    float inv = 1.f / (float)N;
    float mu = stats[c] * inv;
    float var = stats[32 + c] * inv - mu * mu;   // biased, as in ref
    float s = g[c] * rsqrtf(var + BN_EPS);
    sc[c] = s;
    sh[c] = be[c] - mu * s;
  }
}

__global__ void k_copy4(const float4* __restrict__ s, float4* __restrict__ d, int n) {
  int i = blockIdx.x * blockDim.x + threadIdx.x;
  if (i < n) d[i] = s[i];
}

// ---------------- launch ----------------
extern "C" void kernel_launch(void* const* d_in, const int* in_sizes, int n_in,
                              void* d_out, int out_size, void* d_ws, size_t ws_size,
                              hipStream_t stream) {
  const float* x   = (const float*)d_in[0];
  const int*   ei  = (const int*)d_in[1];
  const float* ea  = (const float*)d_in[2];
  const float* W0  = (const float*)d_in[3];
  const float* as0 = (const float*)d_in[4];
  const float* ad0 = (const float*)d_in[5];
  const float* b0  = (const float*)d_in[6];
  const float* g0  = (const float*)d_in[7];
  const float* be0 = (const float*)d_in[8];
  const float* W1  = (const float*)d_in[9];
  const float* as1 = (const float*)d_in[10];
  const float* ad1 = (const float*)d_in[11];
  const float* b1  = (const float*)d_in[12];
  const float* g1  = (const float*)d_in[13];
  const float* be1 = (const float*)d_in[14];
  const float* W2  = (const float*)d_in[15];
  const float* as2 = (const float*)d_in[16];
  const float* ad2 = (const float*)d_in[17];
  const float* b2  = (const float*)d_in[18];

  const int N = in_sizes[0] / 128;
  const int E = in_sizes[1] / 2;
  const int* srcI = ei;
  const int* dstI = ei + E;
  const int NB = (N + 255) >> 8;
  const int nb = NB;

  char* w = (char*)d_ws;
  auto carve = [&](size_t bytes) -> void* {
    void* p = (void*)w;
    w += (bytes + 255) & ~(size_t)255;
    return p;
  };
  unsigned short* h  = (unsigned short*)carve((size_t)N * 128 * 2);
  float* als        = (float*)carve((size_t)N * 4 * 4);
  float* ald        = (float*)carve((size_t)N * 4 * 4);
  float* y          = (float*)carve((size_t)N * 32 * 4);
  int* offs         = (int*)carve((size_t)(N + 1) * 4);
  int* srcs         = (int*)carve((size_t)E * 4);
  // zero-init region: deg + bh + stats covered by ONE memset
  int* deg          = (int*)carve((size_t)N * 4);
  int* bh           = (int*)carve(512 * 4);
  float* stats      = (float*)carve(128 * 4);
  char* zend        = w;
  int* tilesum      = (int*)carve((size_t)nb * 4);
  int* tilepre      = (int*)carve((size_t)nb * 4);
  int* bstart       = (int*)carve(513 * 4);
  int* bcur         = (int*)carve(512 * 4);
  float* bnsc       = (float*)carve(32 * 4);
  float* bnsh       = (float*)carve(32 * 4);
  unsigned short* Wt0 = (unsigned short*)carve(128 * 128 * 2);
  unsigned short* Wt1 = (unsigned short*)carve(128 * 32 * 2);
  unsigned short* Wt2 = (unsigned short*)carve(128 * 32 * 2);
  if ((size_t)(w - (char*)d_ws) > ws_size) {
    fprintf(stderr, "GAT kernel: ws too small (%zu needed, %zu given)\n",
            (size_t)(w - (char*)d_ws), ws_size);
    return;
  }
  uint2* bpair = (uint2*)h;   // aliases h; consumed before h is written

  hipMemsetAsync(deg, 0, (size_t)(zend - (char*)deg), stream);

  k_deg_bhist<<<256, 256, 0, stream>>>(dstI, deg, bh, E);
  k_scan_tile<<<nb, 256, 0, stream>>>(deg, offs, tilesum, N);
  k_exscan2<<<1, 512, 0, stream>>>(tilesum, tilepre, bh, bstart, bcur, nb, offs + N);
  k_addfix<<<(N + 255) / 256, 256, 0, stream>>>(offs, tilepre, N);
  k_bscatter<<<128, 256, 0, stream>>>(srcI, dstI, bcur, bpair, E);
  k_bcsr<<<NB, 256, 0, stream>>>(bpair, bstart, offs, srcs, N);

  k_castW3<<<96, 256, 0, stream>>>(W0, W1, W2, Wt0, Wt1, Wt2);

  const int gGemm = (N + 63) / 64;
  const int gAgg  = (N + 3) / 4;
  float* out_nodes = (float*)d_out;
  float* out_ea    = out_nodes + (size_t)N * 32;

  // layer 0
  k_mfma<128, false><<<gGemm, 256, 0, stream>>>(x, Wt0, as0, ad0, nullptr, nullptr,
                                                h, als, ald, N);
  k_agg<<<gAgg, 256, 0, stream>>>((const unsigned int*)h, als, ald, offs, srcs, b0, y, N);
  k_bnstats<<<512, 256, 0, stream>>>(y, stats, N);
  k_bnfinal<<<1, 32, 0, stream>>>(stats, g0, be0, bnsc, bnsh, N);
  // layer 1 (BN+ReLU fused into GEMM A-load)
  k_mfma<32, true><<<gGemm, 256, 0, stream>>>(y, Wt1, as1, ad1, bnsc, bnsh,
                                              h, als, ald, N);
  k_agg<<<gAgg, 256, 0, stream>>>((const unsigned int*)h, als, ald, offs, srcs, b1, y, N);
  k_bnstats<<<512, 256, 0, stream>>>(y, stats + 64, N);
  k_bnfinal<<<1, 32, 0, stream>>>(stats + 64, g1, be1, bnsc, bnsh, N);
  // layer 2 (writes node output directly to d_out)
  k_mfma<32, true><<<gGemm, 256, 0, stream>>>(y, Wt2, as2, ad2, bnsc, bnsh,
                                              h, als, ald, N);
  k_agg<<<gAgg, 256, 0, stream>>>((const unsigned int*)h, als, ald, offs, srcs, b2,
                                  out_nodes, N);
  // edge_attr passthrough
  const int n4 = E * 2;
  k_copy4<<<(n4 + 255) / 256, 256, 0, stream>>>((const float4*)ea, (float4*)out_ea, n4);
}